// Round 6
// baseline (1862.605 us; speedup 1.0000x reference)
//
#include <hip/hip_runtime.h>

#define T_STEPS 1024
#define HSZ     64
#define OSZ     128

typedef float4 F4;

__device__ __forceinline__ float fast_rcp(float x) { return __builtin_amdgcn_rcpf(x); }
__device__ __forceinline__ float tanh_fast(float x) {
    float e = __expf(2.0f * x);
    return fmaf(-2.0f, fast_rcp(e + 1.0f), 1.0f);
}

// one fma-group of a dot product against named weight reg W, source vs[i]
#define DOT(W, i) { F4 v_ = vs[i]; \
    a0 = fmaf(v_.x, (W).x, a0); a1 = fmaf(v_.y, (W).y, a1); \
    a2 = fmaf(v_.z, (W).z, a2); a3 = fmaf(v_.w, (W).w, a3); }

// gate butterfly: gates of unit j sit in lanes 4j..4j+3 (gt = lane&3).
// q1 = gate gt^1, q2 = gate gt^2, q3 = gate gt^3.
#define GATE_SELECT(act, gt, iv, fv, gv, ov) \
    float q1 = __shfl_xor((act), 1); \
    float q2 = __shfl_xor((act), 2); \
    float q3 = __shfl_xor(q1, 2); \
    const bool b0 = (gt) & 1, b1 = (gt) & 2; \
    float iv = b1 ? (b0 ? q3 : q2) : (b0 ? q1 : (act)); \
    float fv = b1 ? (b0 ? q2 : q3) : (b0 ? (act) : q1); \
    float gv = b1 ? (b0 ? q1 : (act)) : (b0 ? q3 : q2); \
    float ov = b1 ? (b0 ? (act) : q1) : (b0 ? q2 : q3);

// =============== Layer 0: waves 0-3 scan, waves 4-7 x-projection ===========
extern "C" __global__ void __launch_bounds__(512, 2)
lstm_l0(const float* __restrict__ x,      // [B][T][128]
        const float* __restrict__ h0, const float* __restrict__ c0,
        const float* __restrict__ w_ih,   // [256][128]
        const float* __restrict__ w_hh,   // [256][64]
        const float* __restrict__ b_ih, const float* __restrict__ b_hh,
        float* __restrict__ out0,         // [B][T][64] (ws)
        float* __restrict__ hn, float* __restrict__ cn)
{
    const int t_ = threadIdx.x;
    const int b  = blockIdx.x;
    const bool isScan = (t_ < 256);
    const int u  = t_ & 255;
    const int j  = u >> 2;      // scan: hidden unit
    const int gt = u & 3;       // scan: gate

    __shared__ __align__(16) float xbuf[64 * 128];    // 32 KB chunk of x
    __shared__ __align__(16) float obuf[2][64 * HSZ]; // 2x16 KB staged h
    __shared__ __align__(16) float xg[2][256];        // x-projection ping-pong
    __shared__ __align__(16) float hbuf[2][HSZ];      // hidden state ping-pong

    // ---- weights in NAMED registers (no arrays -> guaranteed VGPRs) ----
    F4 W00,W01,W02,W03,W04,W05,W06,W07,W08,W09,W10,W11,W12,W13,W14,W15;
    F4 W16,W17,W18,W19,W20,W21,W22,W23,W24,W25,W26,W27,W28,W29,W30,W31;
    {
        const F4 z = {0.f, 0.f, 0.f, 0.f};
        if (isScan) {
            const F4* ws = reinterpret_cast<const F4*>(w_hh + (size_t)(gt * HSZ + j) * HSZ);
            W00=ws[0]; W01=ws[1]; W02=ws[2];  W03=ws[3];  W04=ws[4];  W05=ws[5];  W06=ws[6];  W07=ws[7];
            W08=ws[8]; W09=ws[9]; W10=ws[10]; W11=ws[11]; W12=ws[12]; W13=ws[13]; W14=ws[14]; W15=ws[15];
            W16=z; W17=z; W18=z; W19=z; W20=z; W21=z; W22=z; W23=z;
            W24=z; W25=z; W26=z; W27=z; W28=z; W29=z; W30=z; W31=z;
        } else {
            const F4* ws = reinterpret_cast<const F4*>(w_ih + (size_t)u * 128);
            W00=ws[0];  W01=ws[1];  W02=ws[2];  W03=ws[3];  W04=ws[4];  W05=ws[5];  W06=ws[6];  W07=ws[7];
            W08=ws[8];  W09=ws[9];  W10=ws[10]; W11=ws[11]; W12=ws[12]; W13=ws[13]; W14=ws[14]; W15=ws[15];
            W16=ws[16]; W17=ws[17]; W18=ws[18]; W19=ws[19]; W20=ws[20]; W21=ws[21]; W22=ws[22]; W23=ws[23];
            W24=ws[24]; W25=ws[25]; W26=ws[26]; W27=ws[27]; W28=ws[28]; W29=ws[29]; W30=ws[30]; W31=ws[31];
        }
    }
    const float bias = isScan ? 0.f : (b_ih[u] + b_hh[u]);  // folded into xg
    const float am = (gt == 2) ? -2.0f : -1.0f;
    const float aa = (gt == 2) ?  2.0f :  1.0f;
    const float ab = (gt == 2) ? -1.0f :  0.0f;

    float c = 0.f, h = 0.f;
    if (isScan) {
        c = c0[(size_t)b * HSZ + j];                 // replicated x4 lanes
        if (gt == 0) hbuf[0][j] = h0[(size_t)b * HSZ + j];
    }
    {   // stage chunk 0 (steps 0..63) — all 512 threads
        const F4* src = reinterpret_cast<const F4*>(x + (size_t)b * T_STEPS * 128);
        F4* dst = reinterpret_cast<F4*>(xbuf);
        #pragma unroll
        for (int k = 0; k < 4; ++k) dst[t_ + 512 * k] = src[t_ + 512 * k];
    }
    __syncthreads();
    if (!isScan) {   // xg for step 0
        const F4* vs = reinterpret_cast<const F4*>(xbuf);
        float a0=0.f,a1=0.f,a2=0.f,a3=0.f;
        DOT(W00,0)  DOT(W01,1)  DOT(W02,2)  DOT(W03,3)  DOT(W04,4)  DOT(W05,5)  DOT(W06,6)  DOT(W07,7)
        DOT(W08,8)  DOT(W09,9)  DOT(W10,10) DOT(W11,11) DOT(W12,12) DOT(W13,13) DOT(W14,14) DOT(W15,15)
        DOT(W16,16) DOT(W17,17) DOT(W18,18) DOT(W19,19) DOT(W20,20) DOT(W21,21) DOT(W22,22) DOT(W23,23)
        DOT(W24,24) DOT(W25,25) DOT(W26,26) DOT(W27,27) DOT(W28,28) DOT(W29,29) DOT(W30,30) DOT(W31,31)
        xg[0][u] = bias + (a0 + a1) + (a2 + a3);
    }
    __syncthreads();

    for (int t = 0; t < T_STEPS; ++t) {
        if (((t & 63) == 63) && t < 1023) {   // stage next chunk (steps t+1..t+64)
            const F4* src = reinterpret_cast<const F4*>(x + ((size_t)b * T_STEPS + t + 1) * 128);
            F4* dst = reinterpret_cast<F4*>(xbuf);
            #pragma unroll
            for (int k = 0; k < 4; ++k) dst[t_ + 512 * k] = src[t_ + 512 * k];
            __syncthreads();
        }
        const int p = t & 1;
        if (isScan) {
            // h-dot: 16 wave-uniform b128 broadcasts + 64 FMAs (W00..W15)
            const F4* vs = reinterpret_cast<const F4*>(hbuf[p]);
            float a0=0.f,a1=0.f,a2=0.f,a3=0.f;
            DOT(W00,0)  DOT(W01,1)  DOT(W02,2)  DOT(W03,3)  DOT(W04,4)  DOT(W05,5)  DOT(W06,6)  DOT(W07,7)
            DOT(W08,8)  DOT(W09,9)  DOT(W10,10) DOT(W11,11) DOT(W12,12) DOT(W13,13) DOT(W14,14) DOT(W15,15)
            float pre = xg[p][gt * HSZ + j] + (a0 + a1) + (a2 + a3);
            float act = fmaf(aa, fast_rcp(1.0f + __expf(am * pre)), ab);
            GATE_SELECT(act, gt, iv, fv, gv, ov)
            c = fmaf(fv, c, iv * gv);
            h = ov * tanh_fast(c);
            if (gt == 0) { hbuf[p ^ 1][j] = h; obuf[(t >> 6) & 1][(t & 63) * HSZ + j] = h; }
        } else {
            if (t < 1023) {   // xg for step t+1
                const F4* vs = reinterpret_cast<const F4*>(xbuf + ((t + 1) & 63) * 128);
                float a0=0.f,a1=0.f,a2=0.f,a3=0.f;
                DOT(W00,0)  DOT(W01,1)  DOT(W02,2)  DOT(W03,3)  DOT(W04,4)  DOT(W05,5)  DOT(W06,6)  DOT(W07,7)
                DOT(W08,8)  DOT(W09,9)  DOT(W10,10) DOT(W11,11) DOT(W12,12) DOT(W13,13) DOT(W14,14) DOT(W15,15)
                DOT(W16,16) DOT(W17,17) DOT(W18,18) DOT(W19,19) DOT(W20,20) DOT(W21,21) DOT(W22,22) DOT(W23,23)
                DOT(W24,24) DOT(W25,25) DOT(W26,26) DOT(W27,27) DOT(W28,28) DOT(W29,29) DOT(W30,30) DOT(W31,31)
                xg[p ^ 1][u] = bias + (a0 + a1) + (a2 + a3);
            }
            if ((t & 63) == 1 && t > 64) {   // flush finished obuf chunk (proj waves only)
                const int cc = (t >> 6) - 1;
                const F4* s4 = reinterpret_cast<const F4*>(obuf[cc & 1]);
                F4* dst = reinterpret_cast<F4*>(out0 + ((size_t)b * T_STEPS + cc * 64) * HSZ);
                #pragma unroll
                for (int k = 0; k < 4; ++k) dst[u + 256 * k] = s4[u + 256 * k];
            }
        }
        __syncthreads();
    }
    {   // flush last chunk (all threads)
        const F4* s4 = reinterpret_cast<const F4*>(obuf[1]);
        F4* dst = reinterpret_cast<F4*>(out0 + ((size_t)b * T_STEPS + 15 * 64) * HSZ);
        #pragma unroll
        for (int k = 0; k < 2; ++k) dst[t_ + 512 * k] = s4[t_ + 512 * k];
    }
    if (isScan && gt == 0) {
        hn[(size_t)b * HSZ + j] = h;
        cn[(size_t)b * HSZ + j] = c;
    }
}

// ========= Layer 1: scan waves + proj waves (x-proj ahead, FC behind) ======
extern "C" __global__ void __launch_bounds__(512, 2)
lstm_l1_fc(const float* __restrict__ in0,   // [B][T][64]
           const float* __restrict__ h0, const float* __restrict__ c0,
           const float* __restrict__ w_ih,  // [256][64]
           const float* __restrict__ w_hh,  // [256][64]
           const float* __restrict__ b_ih, const float* __restrict__ b_hh,
           const float* __restrict__ w_fc,  // [128][64]
           const float* __restrict__ b_fc,  // [128]
           float* __restrict__ logits,      // [B*T][128]
           float* __restrict__ hn, float* __restrict__ cn)
{
    const int t_ = threadIdx.x;
    const int b  = blockIdx.x;
    const bool isScan = (t_ < 256);
    const int u  = t_ & 255;
    const int j  = u >> 2;
    const int gt = u & 3;
    const int o  = u >> 1;     // proj: FC output
    const int hh = u & 1;      // proj: FC dot half

    __shared__ __align__(16) float ibuf[64 * HSZ];     // 16 KB chunk of l0 h
    __shared__ __align__(16) float lbuf[2][64 * OSZ];  // 2x32 KB staged logits
    __shared__ __align__(16) float xg[2][256];
    __shared__ __align__(16) float hbuf[2][HSZ];

    F4 W00,W01,W02,W03,W04,W05,W06,W07,W08,W09,W10,W11,W12,W13,W14,W15;
    F4 W16,W17,W18,W19,W20,W21,W22,W23;
    {
        if (isScan) {
            const F4 z = {0.f, 0.f, 0.f, 0.f};
            const F4* ws = reinterpret_cast<const F4*>(w_hh + (size_t)(gt * HSZ + j) * HSZ);
            W00=ws[0]; W01=ws[1]; W02=ws[2];  W03=ws[3];  W04=ws[4];  W05=ws[5];  W06=ws[6];  W07=ws[7];
            W08=ws[8]; W09=ws[9]; W10=ws[10]; W11=ws[11]; W12=ws[12]; W13=ws[13]; W14=ws[14]; W15=ws[15];
            W16=z; W17=z; W18=z; W19=z; W20=z; W21=z; W22=z; W23=z;
        } else {
            const F4* ws = reinterpret_cast<const F4*>(w_ih + (size_t)u * HSZ);
            W00=ws[0]; W01=ws[1]; W02=ws[2];  W03=ws[3];  W04=ws[4];  W05=ws[5];  W06=ws[6];  W07=ws[7];
            W08=ws[8]; W09=ws[9]; W10=ws[10]; W11=ws[11]; W12=ws[12]; W13=ws[13]; W14=ws[14]; W15=ws[15];
            const F4* wf = reinterpret_cast<const F4*>(w_fc + (size_t)o * HSZ + hh * 32);
            W16=wf[0]; W17=wf[1]; W18=wf[2]; W19=wf[3]; W20=wf[4]; W21=wf[5]; W22=wf[6]; W23=wf[7];
        }
    }
    const float bias = isScan ? 0.f : (b_ih[u] + b_hh[u]);
    const float bfc  = b_fc[o];
    const float am = (gt == 2) ? -2.0f : -1.0f;
    const float aa = (gt == 2) ?  2.0f :  1.0f;
    const float ab = (gt == 2) ? -1.0f :  0.0f;

    float c = 0.f, h = 0.f;
    if (isScan) {
        c = c0[(size_t)b * HSZ + j];
        if (gt == 0) hbuf[0][j] = h0[(size_t)b * HSZ + j];
    }
    {   // stage chunk 0
        const F4* src = reinterpret_cast<const F4*>(in0 + (size_t)b * T_STEPS * HSZ);
        F4* dst = reinterpret_cast<F4*>(ibuf);
        #pragma unroll
        for (int k = 0; k < 2; ++k) dst[t_ + 512 * k] = src[t_ + 512 * k];
    }
    __syncthreads();
    if (!isScan) {
        const F4* vs = reinterpret_cast<const F4*>(ibuf);
        float a0=0.f,a1=0.f,a2=0.f,a3=0.f;
        DOT(W00,0)  DOT(W01,1)  DOT(W02,2)  DOT(W03,3)  DOT(W04,4)  DOT(W05,5)  DOT(W06,6)  DOT(W07,7)
        DOT(W08,8)  DOT(W09,9)  DOT(W10,10) DOT(W11,11) DOT(W12,12) DOT(W13,13) DOT(W14,14) DOT(W15,15)
        xg[0][u] = bias + (a0 + a1) + (a2 + a3);
    }
    __syncthreads();

    for (int t = 0; t < T_STEPS; ++t) {
        if (((t & 63) == 63) && t < 1023) {
            const F4* src = reinterpret_cast<const F4*>(in0 + ((size_t)b * T_STEPS + t + 1) * HSZ);
            F4* dst = reinterpret_cast<F4*>(ibuf);
            #pragma unroll
            for (int k = 0; k < 2; ++k) dst[t_ + 512 * k] = src[t_ + 512 * k];
            __syncthreads();
        }
        const int p = t & 1;
        if (isScan) {
            const F4* vs = reinterpret_cast<const F4*>(hbuf[p]);
            float a0=0.f,a1=0.f,a2=0.f,a3=0.f;
            DOT(W00,0)  DOT(W01,1)  DOT(W02,2)  DOT(W03,3)  DOT(W04,4)  DOT(W05,5)  DOT(W06,6)  DOT(W07,7)
            DOT(W08,8)  DOT(W09,9)  DOT(W10,10) DOT(W11,11) DOT(W12,12) DOT(W13,13) DOT(W14,14) DOT(W15,15)
            float pre = xg[p][gt * HSZ + j] + (a0 + a1) + (a2 + a3);
            float act = fmaf(aa, fast_rcp(1.0f + __expf(am * pre)), ab);
            GATE_SELECT(act, gt, iv, fv, gv, ov)
            c = fmaf(fv, c, iv * gv);
            h = ov * tanh_fast(c);
            if (gt == 0) hbuf[p ^ 1][j] = h;
        } else {
            if (t < 1023) {   // xg for step t+1
                const F4* vs = reinterpret_cast<const F4*>(ibuf + ((t + 1) & 63) * HSZ);
                float a0=0.f,a1=0.f,a2=0.f,a3=0.f;
                DOT(W00,0)  DOT(W01,1)  DOT(W02,2)  DOT(W03,3)  DOT(W04,4)  DOT(W05,5)  DOT(W06,6)  DOT(W07,7)
                DOT(W08,8)  DOT(W09,9)  DOT(W10,10) DOT(W11,11) DOT(W12,12) DOT(W13,13) DOT(W14,14) DOT(W15,15)
                xg[p ^ 1][u] = bias + (a0 + a1) + (a2 + a3);
            }
            if (t > 0) {   // FC for step t-1 (h_{t-1} lives in hbuf[p])
                const F4* vs = reinterpret_cast<const F4*>(&hbuf[p][hh * 32]);
                float a0=0.f,a1=0.f,a2=0.f,a3=0.f;
                DOT(W16,0) DOT(W17,1) DOT(W18,2) DOT(W19,3) DOT(W20,4) DOT(W21,5) DOT(W22,6) DOT(W23,7)
                float f = (a0 + a1) + (a2 + a3);
                f += __shfl_xor(f, 1);
                if (hh == 0) lbuf[((t - 1) >> 6) & 1][((t - 1) & 63) * OSZ + o] = f + bfc;
            }
            if ((t & 63) == 1 && t > 64) {   // flush finished logits chunk
                const int cc = (t >> 6) - 1;
                const F4* s4 = reinterpret_cast<const F4*>(lbuf[cc & 1]);
                F4* dst = reinterpret_cast<F4*>(logits + ((size_t)b * T_STEPS + cc * 64) * OSZ);
                #pragma unroll
                for (int k = 0; k < 8; ++k) dst[u + 256 * k] = s4[u + 256 * k];
            }
        }
        __syncthreads();
    }
    // epilogue: FC for step 1023 (h_1023 is in hbuf[0]), then flush chunk 15
    if (!isScan) {
        const F4* vs = reinterpret_cast<const F4*>(&hbuf[0][hh * 32]);
        float a0=0.f,a1=0.f,a2=0.f,a3=0.f;
        DOT(W16,0) DOT(W17,1) DOT(W18,2) DOT(W19,3) DOT(W20,4) DOT(W21,5) DOT(W22,6) DOT(W23,7)
        float f = (a0 + a1) + (a2 + a3);
        f += __shfl_xor(f, 1);
        if (hh == 0) lbuf[1][63 * OSZ + o] = f + bfc;
    }
    __syncthreads();
    {
        const F4* s4 = reinterpret_cast<const F4*>(lbuf[1]);
        F4* dst = reinterpret_cast<F4*>(logits + ((size_t)b * T_STEPS + 15 * 64) * OSZ);
        #pragma unroll
        for (int k = 0; k < 4; ++k) dst[t_ + 512 * k] = s4[t_ + 512 * k];
    }
    if (isScan && gt == 0) {
        hn[(size_t)b * HSZ + j] = h;
        cn[(size_t)b * HSZ + j] = c;
    }
}

extern "C" void kernel_launch(void* const* d_in, const int* in_sizes, int n_in,
                              void* d_out, int out_size, void* d_ws, size_t ws_size,
                              hipStream_t stream) {
    const float* x     = (const float*)d_in[0];
    const float* h0    = (const float*)d_in[1];
    const float* c0    = (const float*)d_in[2];
    const float* w_ih0 = (const float*)d_in[3];
    const float* w_hh0 = (const float*)d_in[4];
    const float* b_ih0 = (const float*)d_in[5];
    const float* b_hh0 = (const float*)d_in[6];
    const float* w_ih1 = (const float*)d_in[7];
    const float* w_hh1 = (const float*)d_in[8];
    const float* b_ih1 = (const float*)d_in[9];
    const float* b_hh1 = (const float*)d_in[10];
    const float* w_fc  = (const float*)d_in[11];
    const float* b_fc  = (const float*)d_in[12];

    float* out = (float*)d_out;
    const size_t n_logits = (size_t)256 * T_STEPS * OSZ;
    const size_t n_state  = (size_t)256 * HSZ;
    float* logits = out;
    float* hn     = out + n_logits;
    float* cn     = hn + 2 * n_state;

    float* out0 = (float*)d_ws;   // [256][1024][64]

    lstm_l0<<<256, 512, 0, stream>>>(
        x, h0, c0, w_ih0, w_hh0, b_ih0, b_hh0, out0, hn, cn);

    lstm_l1_fc<<<256, 512, 0, stream>>>(
        out0, h0 + n_state, c0 + n_state,
        w_ih1, w_hh1, b_ih1, b_hh1, w_fc, b_fc,
        logits, hn + n_state, cn + n_state);
}